// Round 8
// baseline (29976.895 us; speedup 1.0000x reference)
//
#include <hip/hip_runtime.h>
#include <hip/hip_bf16.h>
#include <stdint.h>

// ---------------------------------------------------------------------------
// BioDecoder: 64-step LSTM decoder w/ attention, rep-penalty, temperature=0.4,
// top-p=0.7, jax.random.categorical (Threefry partitionable). All fp32.
// Association discipline: every dot = strict sequential-k single-acc fma chain.
// R10: (1) REVERT R9's gate fusion (it made each of 64 blocks stream all 4MB
// of Wg1 -> 256MB/step; separate 32-block GEMM reads 4MB total). (2) GEMM
// thread geometry: layer/gate <32,2,4,256> (8 outputs/thread, halves the
// per-SIMD fma chain, all 1024 SIMDs covered), logits <64,4,4,256> x500
// (2 blocks/CU for latency hiding). Output->thread mapping changes only;
// every output's k-chain association is untouched -> bit-exact.
// Keeps R9's register-resident sampler (real win, was masked by fusion).
// ---------------------------------------------------------------------------

#define B_   64
#define H_   1024
#define E_   512
#define DV_  512
#define KV_  49
#define V_   32000
#define T_   64

// ------------------------- Threefry-2x32-20 (JAX) --------------------------
__device__ __forceinline__ uint32_t rotl32(uint32_t x, int r) {
  return (x << r) | (x >> (32 - r));
}
__device__ __forceinline__ void tf2x32(uint32_t k0, uint32_t k1,
                                       uint32_t x0, uint32_t x1,
                                       uint32_t& o0, uint32_t& o1) {
  uint32_t ks0 = k0, ks1 = k1, ks2 = k0 ^ k1 ^ 0x1BD11BDAu;
  x0 += ks0; x1 += ks1;
#define RND_(r) { x0 += x1; x1 = rotl32(x1, r) ^ x0; }
  RND_(13) RND_(15) RND_(26) RND_(6)  x0 += ks1; x1 += ks2 + 1u;
  RND_(17) RND_(29) RND_(16) RND_(24) x0 += ks2; x1 += ks0 + 2u;
  RND_(13) RND_(15) RND_(26) RND_(6)  x0 += ks0; x1 += ks1 + 3u;
  RND_(17) RND_(29) RND_(16) RND_(24) x0 += ks1; x1 += ks2 + 4u;
  RND_(13) RND_(15) RND_(26) RND_(6)  x0 += ks2; x1 += ks0 + 5u;
#undef RND_
  o0 = x0; o1 = x1;
}

__device__ __forceinline__ unsigned key_of(float f) {
  unsigned u = __float_as_uint(f);
  return (u & 0x80000000u) ? ~u : (u | 0x80000000u);
}
__device__ __forceinline__ float sigf(float x) { return 1.0f / (1.0f + expf(-x)); }

// ------------------------- templated dual GEMM -----------------------------
// out[m][n] = sum_k A[m][k]*W[n][k], k ascending, one fma chain per output.
// BM fixed = 64. BK = 32. Unified LDS: rows 0..63 = A tile, 64..64+BN-1 = W.
// XOR column swizzle; reg-prefetch double buffer; 1 barrier per chunk.
template <int BN, int TM, int TN, int NTHR>
__global__ __launch_bounds__(NTHR)
void gemm_dq(const float* __restrict__ A0, int lda0, const float* __restrict__ W0,
             int ldw0, int K0, float* __restrict__ out0, int ldo0, int nt0,
             const float* __restrict__ A1, int lda1, const float* __restrict__ W1,
             int ldw1, int K1, float* __restrict__ out1, int ldo1) {
  constexpr int LD = 36;
  constexpr int ROWS = 64 + BN;
  constexpr int NF4 = ROWS * 8 / NTHR;
  constexpr int BUFST = ROWS * LD;
  constexpr int CG = BN / TN;
  static_assert(ROWS * 8 % NTHR == 0, "staging divisibility");
  static_assert((64 / TM) * CG == NTHR, "thread grid");
  static_assert(TN == 4, "float4 epilogue");
  __shared__ __align__(16) float S[2][ROWS][LD];

  const int tid = threadIdx.x;
  const int bx = blockIdx.x;
  const float* A; const float* W; float* out;
  int lda, ldw, K, ldo, n0;
  if (bx < nt0) { A = A0; W = W0; out = out0; lda = lda0; ldw = ldw0; K = K0; ldo = ldo0; n0 = bx * BN; }
  else          { A = A1; W = W1; out = out1; lda = lda1; ldw = ldw1; K = K1; ldo = ldo1; n0 = (bx - nt0) * BN; }
  const int m0 = blockIdx.y * 64;
  const int tc = tid % CG, tr = tid / CG;

  const float* gp[NF4];
  float* lp[NF4];
#pragma unroll
  for (int q = 0; q < NF4; ++q) {
    int l = tid + q * NTHR;
    int r = l >> 3, c4 = l & 7;
    gp[q] = (l < 512) ? (A + (m0 + r) * lda + c4 * 4)
                      : (W + (n0 + (r - 64)) * ldw + c4 * 4);
    lp[q] = &S[0][r][(c4 ^ ((r >> 2) & 7)) << 2];
  }

  float4 pre[NF4];
#pragma unroll
  for (int q = 0; q < NF4; ++q) pre[q] = *(const float4*)gp[q];
#pragma unroll
  for (int q = 0; q < NF4; ++q) *(float4*)lp[q] = pre[q];
  __syncthreads();

  float acc[TM][TN] = {};
  const int nch = K >> 5;
  for (int c = 0; c < nch; ++c) {
    const bool more = (c + 1 < nch);
    if (more) {
      const int kc = (c + 1) << 5;
#pragma unroll
      for (int q = 0; q < NF4; ++q) pre[q] = *(const float4*)(gp[q] + kc);
    }
    const float* Sb = &S[c & 1][0][0];
#pragma unroll
    for (int kk = 0; kk < 8; ++kk) {
      float4 a4[TM], w4[TN];
#pragma unroll
      for (int i = 0; i < TM; ++i) {
        int m = tr * TM + i;
        a4[i] = *(const float4*)(Sb + m * LD + ((kk ^ ((m >> 2) & 7)) << 2));
      }
#pragma unroll
      for (int j = 0; j < TN; ++j) {
        int rw = 64 + tc * TN + j;
        w4[j] = *(const float4*)(Sb + rw * LD + ((kk ^ ((rw >> 2) & 7)) << 2));
      }
#pragma unroll
      for (int i = 0; i < TM; ++i)
#pragma unroll
        for (int j = 0; j < TN; ++j) {
          acc[i][j] = fmaf(a4[i].x, w4[j].x, acc[i][j]);
          acc[i][j] = fmaf(a4[i].y, w4[j].y, acc[i][j]);
          acc[i][j] = fmaf(a4[i].z, w4[j].z, acc[i][j]);
          acc[i][j] = fmaf(a4[i].w, w4[j].w, acc[i][j]);
        }
    }
    if (more) {
      const int bo2 = ((c + 1) & 1) * BUFST;
#pragma unroll
      for (int q = 0; q < NF4; ++q) *(float4*)(lp[q] + bo2) = pre[q];
    }
    __syncthreads();
  }

#pragma unroll
  for (int i = 0; i < TM; ++i) {
    float4 o;
    o.x = acc[i][0]; o.y = acc[i][1]; o.z = acc[i][2]; o.w = acc[i][3];
    *(float4*)&out[(m0 + tr * TM + i) * ldo + n0 + tc * TN] = o;
  }
}

// ------------------------- LayerNorm for vp (verbatim R6) ------------------
__global__ __launch_bounds__(256)
void ln_vp(float* __restrict__ vp, const float* __restrict__ bv,
           const float* __restrict__ g, const float* __restrict__ bt) {
  int row = blockIdx.x, tid = threadIdx.x;
  __shared__ float buf[H_];
  __shared__ float red[256];
  float* p = vp + (long long)row * H_;
  for (int h = tid; h < H_; h += 256) buf[h] = __fadd_rn(p[h], bv[h]);
  __syncthreads();
  float s = 0;
  for (int h = tid; h < H_; h += 256) s += buf[h];
  red[tid] = s; __syncthreads();
  for (int off = 128; off > 0; off >>= 1) { if (tid < off) red[tid] += red[tid + off]; __syncthreads(); }
  float mu = red[0] / (float)H_;
  __syncthreads();
  float vs = 0;
  for (int h = tid; h < H_; h += 256) { float d = buf[h] - mu; vs += d * d; }
  red[tid] = vs; __syncthreads();
  for (int off = 128; off > 0; off >>= 1) { if (tid < off) red[tid] += red[tid + off]; __syncthreads(); }
  float var = red[0] / (float)H_;
  float sq = sqrtf(var + 1e-5f);
  for (int h = tid; h < H_; h += 256) {
    float nrm = __fdiv_rn(__fsub_rn(buf[h], mu), sq);
    p[h] = __fadd_rn(__fmul_rn(nrm, g[h]), bt[h]);
  }
}

// ------------------------- LSTM cell (verbatim R6) -------------------------
__global__ __launch_bounds__(256)
void lstm_cell2(const float* __restrict__ dx, const float* __restrict__ dh,
                const float* __restrict__ bih, const float* __restrict__ bhh,
                float* __restrict__ c,
                float* __restrict__ hA, int ldA, float* __restrict__ hB, int ldB) {
  int idx = blockIdx.x * 256 + threadIdx.x;      // 64*1024
  int b = idx >> 10, h = idx & 1023;
  float z[4];
#pragma unroll
  for (int g = 0; g < 4; g++) {
    int j = g * 1024 + h;
    float s = __fadd_rn(dx[b * 4096 + j], dh[b * 4096 + j]);
    s = __fadd_rn(s, bih[j]);
    s = __fadd_rn(s, bhh[j]);
    z[g] = s;
  }
  float fc = __fmul_rn(sigf(z[1]), c[idx]);
  float ig = __fmul_rn(sigf(z[0]), tanhf(z[2]));
  float cn = __fadd_rn(fc, ig);
  float hn = __fmul_rn(sigf(z[3]), tanhf(cn));
  c[idx] = cn;
  hA[(long long)b * ldA + h] = hn;
  hB[(long long)b * ldB + h] = hn;
}

// ------------------------- gate + attention (verbatim R6) ------------------
__global__ __launch_bounds__(256)
void gate_attn(const float* __restrict__ dg, const float* __restrict__ bg1,
               const float* __restrict__ Wg2, const float* __restrict__ bg2,
               const float* __restrict__ h2buf, const float* __restrict__ vp,
               float* __restrict__ ctx) {
  int b = blockIdx.x, tid = threadIdx.x;
  __shared__ float t1[H_], outv[H_], attn[64];
  __shared__ float gate_s;
  for (int h = tid; h < H_; h += 256)
    t1[h] = tanhf(__fadd_rn(dg[b * H_ + h], bg1[h]));
  __syncthreads();
  if (tid == 0) {
    float s = 0;
    for (int h = 0; h < H_; h++) s = fmaf(t1[h], Wg2[h], s);
    gate_s = sigf(__fadd_rn(s, bg2[0]));
  }
  __syncthreads();
  float gate = gate_s;
  for (int h = tid; h < H_; h += 256) outv[h] = __fmul_rn(h2buf[b * H_ + h], gate);
  __syncthreads();
  if (tid < KV_) {
    const float* vrow = vp + ((long long)b * KV_ + tid) * H_;
    float a = 0;
    for (int h = 0; h < H_; h++) a = fmaf(outv[h], vrow[h], a);
    attn[tid] = __fmul_rn(a, 0.03125f);   // scale = 1/sqrt(1024)
  }
  __syncthreads();
  if (tid == 0) {
    float m = -INFINITY;
    for (int k = 0; k < KV_; k++) m = fmaxf(m, attn[k]);
    float ss = 0;
    for (int k = 0; k < KV_; k++) { attn[k] = expf(attn[k] - m); ss += attn[k]; }
    for (int k = 0; k < KV_; k++) attn[k] = __fdiv_rn(attn[k], ss);
  }
  __syncthreads();
  for (int h = tid; h < H_; h += 256) {
    float acc = 0;
    for (int k = 0; k < KV_; k++) acc = fmaf(attn[k], vp[((long long)b * KV_ + k) * H_ + h], acc);
    ctx[b * H_ + h] = __fadd_rn(outv[h], acc);
  }
}

// ------------------------- init (verbatim R6) ------------------------------
__global__ __launch_bounds__(256)
void init_state(const float* __restrict__ thought, const float* __restrict__ embedding,
                float* c1, float* c2, float* xcat1, float* xcat2,
                int* hist, int* histv) {
  int i = blockIdx.x * 256 + threadIdx.x;
  if (i < B_ * H_) {
    int b = i >> 10, h = i & 1023;
    c1[i] = 0.f; c2[i] = 0.f;
    float th = thought[i];
    xcat1[b * (E_ + H_) + E_ + h] = th;   // h1_0 = thought
    xcat2[b * (2 * H_) + H_ + h] = th;    // h2_0 = thought
    if (h < E_) xcat1[b * (E_ + H_) + h] = embedding[E_ + h];  // token 1
  }
  if (i < B_ * 3) { hist[i] = 0; histv[i] = 0; }
}

// ------------------------- sampling (verbatim R9, register-resident) -------
__global__ __launch_bounds__(1024)
void sample_kernel(const float* __restrict__ dlog, const float* __restrict__ bo,
                   int* __restrict__ hist, int* __restrict__ histv,
                   const float* __restrict__ embedding, float* __restrict__ xcat1,
                   int* __restrict__ outTok, int t) {
  int b = blockIdx.x, tid = threadIdx.x;
  __shared__ float redf[1024];
  __shared__ int   redi[1024];
  __shared__ unsigned long long whist[8][257];   // 16.4 KB, bank-staggered
  __shared__ unsigned long long suf[256];
  __shared__ unsigned long long wq[4];
  __shared__ int jstar_s;
  __shared__ unsigned long long carry_s;
  __shared__ unsigned prefix_s;

  int hh0 = hist[b * 3 + 0], hh1 = hist[b * 3 + 1], hh2 = hist[b * 3 + 2];
  int p0 = histv[b * 3 + 0] ? hh0 : -1;
  int p1 = histv[b * 3 + 1] ? hh1 : -1;
  int p2 = histv[b * 3 + 2] ? hh2 : -1;
  const float* pa = dlog + (long long)b * V_;

  // pass 1: scaled logits into registers + max
  float L[32];
  float lm = -INFINITY;
#pragma unroll
  for (int e = 0; e < 32; ++e) {
    int v = tid + (e << 10);
    float l = -INFINITY;
    if (v < V_) {
      float raw = __fadd_rn(pa[v], bo[v]);
      if (v == p0 || v == p1 || v == p2) raw = __fsub_rn(raw, 2.0f);
      l = __fdiv_rn(raw, 0.4f);
      lm = fmaxf(lm, l);
    }
    L[e] = l;
  }
  redf[tid] = lm; __syncthreads();
  for (int off = 512; off > 0; off >>= 1) { if (tid < off) redf[tid] = fmaxf(redf[tid], redf[tid + off]); __syncthreads(); }
  float m = redf[0];
  __syncthreads();

  // pass 2: exp + sum
  float ls = 0;
#pragma unroll
  for (int e = 0; e < 32; ++e) {
    int v = tid + (e << 10);
    if (v < V_) ls += expf(L[e] - m);
  }
  redf[tid] = ls; __syncthreads();
  for (int off = 512; off > 0; off >>= 1) { if (tid < off) redf[tid] += redf[tid + off]; __syncthreads(); }
  float Z = redf[0];
  __syncthreads();

  // radix select: K* = key of smallest kept token; kept iff mass(keys>k) <= 0.7f
  const double SC = 17592186044416.0; // 2^44
  const unsigned long long B0 =
      (unsigned long long)(0.699999988079071044921875 * 17592186044416.0); // (double)0.7f * 2^44
  if (tid == 0) { carry_s = 0ull; prefix_s = 0u; }
  __syncthreads();
  const int wid = tid >> 7;   // 8 sub-histograms (2 waves each)
  for (int pass = 0; pass < 4; pass++) {
    int shift = 24 - 8 * pass;
    unsigned maskk = (pass == 0) ? 0u : (0xFFFFFFFFu << (shift + 8));
    for (int i = tid; i < 8 * 257; i += 1024) ((unsigned long long*)whist)[i] = 0ull;
    __syncthreads();
    unsigned pref = prefix_s;
    unsigned long long carry = carry_s;
#pragma unroll
    for (int e = 0; e < 32; ++e) {
      int v = tid + (e << 10);
      if (v < V_) {
        unsigned key = key_of(L[e]);
        if ((key & maskk) == pref) {
          unsigned bin = (key >> shift) & 255u;
          float ee = expf(L[e] - m);   // bit-identical to stored-E variant
          unsigned long long S = (unsigned long long)((double)(ee / Z) * SC);
          atomicAdd(&whist[wid][bin], (S << 16) | 1ull);
        }
      }
    }
    __syncthreads();

    // reduce 8 histograms + shfl suffix scan over 256 bins (tid<256)
    unsigned long long bs = 0ull;
    if (tid < 256) {
#pragma unroll
      for (int w = 0; w < 8; ++w) bs += whist[w][tid];
    }
    if (tid == 0) jstar_s = 256;
    __syncthreads();
    unsigned long long sown = 0ull, sincl = 0ull;
    if (tid < 256) {
      sown = bs >> 16;
      sincl = sown;
#pragma unroll
      for (int off = 1; off < 64; off <<= 1) {
        unsigned long long o = __shfl_down(sincl, off);
        if ((tid & 63) + off < 64) sincl += o;
      }
      if ((tid & 63) == 0) wq[tid >> 6] = sincl;
    }
    __syncthreads();
    if (tid < 256) {
      unsigned long long add = 0ull;
      for (int w2 = (tid >> 6) + 1; w2 < 4; ++w2) add += wq[w2];
      suf[tid] = sincl + add - sown;       // mass strictly above bin tid
    }
    __syncthreads();
    if (tid < 256 && (unsigned)(bs & 0xFFFFull) > 0u) {
      unsigned long long A = carry + suf[tid];
      if (A <= B0) atomicMin(&jstar_s, tid);
    }
    __syncthreads();
    if (tid == 0) {
      int j = jstar_s;
      carry_s = carry + suf[j];
      prefix_s = pref | (((unsigned)j) << shift);
    }
    __syncthreads();
  }
  unsigned Kstar = prefix_s;

  // step key (partitionable foldlike split of key(42))
  unsigned kt0, kt1;
  tf2x32(0u, 42u, 0u, (unsigned)t, kt0, kt1);

  // gumbel argmax over kept set
  float bestv = -INFINITY; int besti = 0x7fffffff;
#pragma unroll
  for (int e = 0; e < 32; ++e) {
    int v = tid + (e << 10);
    if (v < V_) {
      float l = L[e];
      if (key_of(l) >= Kstar) {
        unsigned r0, r1;
        tf2x32(kt0, kt1, 0u, (unsigned)(b * V_ + v), r0, r1);
        unsigned bits = r0 ^ r1;
        float u = __uint_as_float((bits >> 9) | 0x3f800000u) - 1.0f;
        u = fmaxf(u, 1.17549435e-38f);
        float gum = -logf(-logf(u));
        float val = __fadd_rn(l, gum);
        if (val > bestv) { bestv = val; besti = v; }
      }
    }
  }
  redf[tid] = bestv; redi[tid] = besti; __syncthreads();
  for (int off = 512; off > 0; off >>= 1) {
    if (tid < off) {
      float ov = redf[tid + off]; int oi = redi[tid + off];
      if (ov > redf[tid] || (ov == redf[tid] && oi < redi[tid])) { redf[tid] = ov; redi[tid] = oi; }
    }
    __syncthreads();
  }
  int tok = redi[0];
  if (tid == 0) {
    outTok[b * T_ + t] = tok;
    hist[b * 3 + 0] = hh1; hist[b * 3 + 1] = hh2; hist[b * 3 + 2] = tok;
    int v1 = histv[b * 3 + 1], v2 = histv[b * 3 + 2];
    histv[b * 3 + 0] = v1; histv[b * 3 + 1] = v2; histv[b * 3 + 2] = 1;
  }
  // next-step embedding gather
  for (int k = tid; k < E_; k += 1024)
    xcat1[b * (E_ + H_) + k] = embedding[(long long)tok * E_ + k];
}

// ---------------------------------------------------------------------------
extern "C" void kernel_launch(void* const* d_in, const int* in_sizes, int n_in,
                              void* d_out, int out_size, void* d_ws, size_t ws_size,
                              hipStream_t stream) {
  const float* thought   = (const float*)d_in[0];
  const float* visf      = (const float*)d_in[1];
  const float* embedding = (const float*)d_in[3];
  const float* Wih1 = (const float*)d_in[4];
  const float* Whh1 = (const float*)d_in[5];
  const float* bih1 = (const float*)d_in[6];
  const float* bhh1 = (const float*)d_in[7];
  const float* Wih2 = (const float*)d_in[8];
  const float* Whh2 = (const float*)d_in[9];
  const float* bih2 = (const float*)d_in[10];
  const float* bhh2 = (const float*)d_in[11];
  const float* Wg1  = (const float*)d_in[12];
  const float* bg1  = (const float*)d_in[13];
  const float* Wg2  = (const float*)d_in[14];
  const float* bg2  = (const float*)d_in[15];
  const float* Wo   = (const float*)d_in[16];
  const float* bo   = (const float*)d_in[17];
  const float* Wv   = (const float*)d_in[18];
  const float* bv   = (const float*)d_in[19];
  const float* ln_g = (const float*)d_in[20];
  const float* ln_b = (const float*)d_in[21];
  int* outTok = (int*)d_out;

  // workspace layout (floats)
  float* ws = (float*)d_ws;
  long long off = 0;
  float* vp    = ws + off; off += (long long)B_ * KV_ * H_;   // 3,211,264
  float* xcat1 = ws + off; off += B_ * (E_ + H_);
  float* xcat2 = ws + off; off += B_ * (2 * H_);
  float* c1    = ws + off; off += B_ * H_;
  float* c2    = ws + off; off += B_ * H_;
  float* h2buf = ws + off; off += B_ * H_;
  float* ctx   = ws + off; off += B_ * H_;
  float* dx    = ws + off; off += (long long)B_ * 4096;
  float* dh    = ws + off; off += (long long)B_ * 4096;
  float* dg    = ws + off; off += (long long)B_ * H_;
  float* dlog  = ws + off; off += (long long)B_ * V_;
  int* hist  = (int*)(ws + off); off += 256;   // 192 used, padded
  int* histv = (int*)(ws + off); off += 256;   // 192 used, padded

  // init recurrent state
  init_state<<<256, 256, 0, stream>>>(thought, embedding, c1, c2, xcat1, xcat2, hist, histv);

  // visual_proj: vp_pre = visf @ Wv^T (M=3136, N=1024, K=512), then LN(+bv)
  gemm_dq<128, 8, 4, 256><<<dim3(8, KV_), 256, 0, stream>>>(
      visf, DV_, Wv, DV_, DV_, vp, H_, 8,
      visf, DV_, Wv, DV_, DV_, vp, H_);
  ln_vp<<<B_ * KV_, 256, 0, stream>>>(vp, bv, ln_g, ln_b);

  for (int t = 0; t < T_; t++) {
    // layer 1: dx = emb @ Wih1^T (K=512), dh = h1 @ Whh1^T (K=1024) — one launch
    gemm_dq<32, 2, 4, 256><<<dim3(256, 1), 256, 0, stream>>>(
        xcat1, E_ + H_, Wih1, E_, E_, dx, 4096, 128,
        xcat1 + E_, E_ + H_, Whh1, H_, H_, dh, 4096);
    lstm_cell2<<<256, 256, 0, stream>>>(dx, dh, bih1, bhh1, c1,
                                        xcat1 + E_, E_ + H_, xcat2, 2 * H_);
    // layer 2: dx = h1 @ Wih2^T, dh = h2 @ Whh2^T — one launch
    gemm_dq<32, 2, 4, 256><<<dim3(256, 1), 256, 0, stream>>>(
        xcat2, 2 * H_, Wih2, H_, H_, dx, 4096, 128,
        xcat2 + H_, 2 * H_, Whh2, H_, H_, dh, 4096);
    lstm_cell2<<<256, 256, 0, stream>>>(dx, dh, bih2, bhh2, c2,
                                        h2buf, H_, xcat2 + H_, 2 * H_);
    // gate pre-activation: dg = h2 @ Wg1^T (N=1024 -> 32 blocks)
    gemm_dq<32, 2, 4, 256><<<dim3(32, 1), 256, 0, stream>>>(
        h2buf, H_, Wg1, H_, H_, dg, H_, 32,
        h2buf, H_, Wg1, H_, H_, dg, H_);
    gate_attn<<<B_, 256, 0, stream>>>(dg, bg1, Wg2, bg2, h2buf, vp, ctx);
    // logits = ctx @ Wo^T (N=32000 -> 500 blocks of BN=64, 2 blocks/CU)
    gemm_dq<64, 4, 4, 256><<<dim3(500, 1), 256, 0, stream>>>(
        ctx, H_, Wo, H_, H_, dlog, V_, 500,
        ctx, H_, Wo, H_, H_, dlog, V_);
    sample_kernel<<<B_, 1024, 0, stream>>>(dlog, bo, hist, histv,
                                           embedding, xcat1, outTok, t);
  }
}